// Round 9
// baseline (471.627 us; speedup 1.0000x reference)
//
#include <hip/hip_runtime.h>
#include <hip/hip_bf16.h>
#include <math.h>

#define DIM 512
#define NHEAD 8
#define HD 64
#define BATCH 2
#define SEQ 4096
#define CTXLEN 77
#define NTOK (BATCH*SEQ)     // 8192
#define NCTX (BATCH*CTXLEN)  // 154

typedef __hip_bfloat16 bf16;
typedef __attribute__((ext_vector_type(8))) short bf8_t;   // 8 bf16 (4 VGPRs)
typedef __attribute__((ext_vector_type(4))) float f4_t;    // 4 fp32 acc

__device__ __forceinline__ float b2f(bf16 v){ return __bfloat162float(v); }
__device__ __forceinline__ bf16  f2b(float v){ return __float2bfloat16(v); }
// fast bf16 pair pack: round-half-up + one v_perm_b32; low element = a, high = b
__device__ __forceinline__ unsigned int packbf2(float a, float b){
    unsigned int au = __float_as_uint(a) + 0x8000u;
    unsigned int bu = __float_as_uint(b) + 0x8000u;
    return __builtin_amdgcn_perm(bu, au, 0x07060302u);
}
__device__ __forceinline__ void  stf(float* p, float v){ *p = v; }
__device__ __forceinline__ void  stf(bf16* p, float v){ *p = f2b(v); }

// ---------------- fused prep: 8 weight transposes + gw + ow + ctx cast + LN1 ----------------
// Flat block ranges:
//   [0,2048)       : 8 attention weight transposes (512x512)
//   [2048,4096)    : gw transpose  (512 -> 4096)
//   [4096,5120)    : ow transpose  (2048 -> 512)
//   [5120,5428)    : ctx f32->bf16 cast (308*256 == NCTX*DIM)
//   [5428,7476)    : LayerNorm #1 on x (independent of the above; 4 rows/block)
struct PrepArgs {
    const float* src8[8]; bf16* dst8[8];
    const float* gw; bf16* gwT;
    const float* ow; bf16* owT;
    const float* ctx; bf16* ctxb;
    const float* x; const float* lng; const float* lnb; bf16* An;
};
__global__ __launch_bounds__(256)
void prep_kernel(PrepArgs a)
{
    __shared__ float tile[32][33];
    const int bid = blockIdx.x;
    const int tx = threadIdx.x & 31, ty = threadIdx.x >> 5;
    const float* W; bf16* Wt; int K, N, n0, k0;
    if (bid < 2048) {
        int z = bid >> 8, t = bid & 255;
        W = a.src8[z]; Wt = a.dst8[z]; K = 512; N = 512;
        n0 = (t & 15)*32; k0 = (t >> 4)*32;
    } else if (bid < 4096) {
        int t = bid - 2048;
        W = a.gw; Wt = a.gwT; K = 512; N = 4096;
        n0 = (t & 127)*32; k0 = (t >> 7)*32;
    } else if (bid < 5120) {
        int t = bid - 4096;
        W = a.ow; Wt = a.owT; K = 2048; N = 512;
        n0 = (t & 15)*32; k0 = (t >> 4)*32;
    } else if (bid < 5428) {
        int i = (bid - 5120)*256 + threadIdx.x;
        a.ctxb[i] = f2b(a.ctx[i]);
        return;
    } else {
        // LayerNorm #1
        int row  = (bid - 5428)*4 + (threadIdx.x >> 6);
        int lane = threadIdx.x & 63;
        const float* xr = a.x + (size_t)row * DIM;
        float v[8];
        float s = 0.f, sq = 0.f;
        #pragma unroll
        for (int j = 0; j < 8; ++j) {
            float f = xr[lane + 64*j];
            v[j] = f; s += f; sq += f*f;
        }
        #pragma unroll
        for (int off = 32; off; off >>= 1) {
            s  += __shfl_xor(s,  off);
            sq += __shfl_xor(sq, off);
        }
        float mean = s * (1.f/DIM);
        float var  = sq * (1.f/DIM) - mean*mean;
        float rstd = rsqrtf(var + 1e-5f);
        bf16* orow = a.An + (size_t)row * DIM;
        #pragma unroll
        for (int j = 0; j < 8; ++j) {
            int c = lane + 64*j;
            orow[c] = f2b((v[j]-mean)*rstd*a.lng[c] + a.lnb[c]);
        }
        return;
    }
    #pragma unroll
    for (int p = 0; p < 4; ++p)
        tile[ty + p*8][tx] = W[(size_t)(k0 + ty + p*8)*N + n0 + tx];
    __syncthreads();
    #pragma unroll
    for (int p = 0; p < 4; ++p)
        Wt[(size_t)(n0 + ty + p*8)*K + k0 + tx] = f2b(tile[tx][ty + p*8]);
}

// ---------------- LayerNorm (for ln2/ln3, mid-pipeline) ----------------
__global__ __launch_bounds__(256)
void ln_kernel(const float* __restrict__ x, const float* __restrict__ g,
               const float* __restrict__ b, bf16* __restrict__ out, int nrows)
{
    int row  = blockIdx.x * 4 + (threadIdx.x >> 6);
    int lane = threadIdx.x & 63;
    if (row >= nrows) return;
    const float* xr = x + (size_t)row * DIM;
    float v[8];
    float s = 0.f, sq = 0.f;
    #pragma unroll
    for (int j = 0; j < 8; ++j) {
        float f = xr[lane + 64*j];
        v[j] = f; s += f; sq += f*f;
    }
    #pragma unroll
    for (int off = 32; off; off >>= 1) {
        s  += __shfl_xor(s,  off);
        sq += __shfl_xor(sq, off);
    }
    float mean = s * (1.f/DIM);
    float var  = sq * (1.f/DIM) - mean*mean;
    float rstd = rsqrtf(var + 1e-5f);
    bf16* orow = out + (size_t)row * DIM;
    #pragma unroll
    for (int j = 0; j < 8; ++j) {
        int c = lane + 64*j;
        orow[c] = f2b((v[j]-mean)*rstd*g[c] + b[c]);
    }
}

// ---------------- MFMA GEMM with register-prefetch double-buffer (R10 form) ----------------
// VT=1: QKV self -- V columns (p[2]) written directly in transposed attention
//       layout [ (b*8+h)*64+d ][ tok ], pitch SEQ, packed 8B stores.
// VT=2: cross KV -- V columns (p[1]) written transposed to pitch-128 buffer,
//       scalar stores (batch boundary at t=77 is unaligned).
struct OutPtrs { void* p[3]; };
template<int RESID, typename OUTT, bool GUARD, int VT>
__global__ __launch_bounds__(256)
void gemm_mfma_kernel(const bf16* __restrict__ A, const bf16* __restrict__ Wt,
                      const float* __restrict__ bias, const float* __restrict__ resid,
                      OutPtrs outs, int M, int K)
{
    __shared__ __align__(16) unsigned short As[128*64];
    __shared__ __align__(16) unsigned short Bs[64*64];
    const int tid  = threadIdx.x;
    const int wave = tid >> 6, lane = tid & 63;
    const int l16  = lane & 15, quad = lane >> 4;
    const int wm = (wave >> 1) * 64, wn = (wave & 1) * 32;
    const int m0 = blockIdx.y * 128, n0 = blockIdx.x * 64;
    OUTT* outp = (OUTT*)outs.p[n0 >> 9];
    const int lc0 = n0 & 511;
    const int sr = tid >> 3, sc_ = tid & 7;   // staging row/chunk

    f4_t acc[4][2];
    #pragma unroll
    for (int i = 0; i < 4; ++i) { acc[i][0] = f4_t{0,0,0,0}; acc[i][1] = f4_t{0,0,0,0}; }

    // prologue: prefetch k0=0 tiles into registers
    bf8_t pa[4], pb[2];
    #pragma unroll
    for (int p = 0; p < 4; ++p) {
        int r = sr + p*32;
        int gr = m0 + r;
        if (GUARD) gr = (gr < M) ? gr : (M-1);
        pa[p] = *(const bf8_t*)(A + (size_t)gr*K + sc_*8);
    }
    #pragma unroll
    for (int p = 0; p < 2; ++p)
        pb[p] = *(const bf8_t*)(Wt + (size_t)(n0 + sr + p*32)*K + sc_*8);

    for (int k0 = 0; k0 < K; k0 += 64) {
        // regs -> LDS
        #pragma unroll
        for (int p = 0; p < 4; ++p) {
            int r = sr + p*32;
            *(bf8_t*)&As[r*64 + ((sc_ ^ (r&7))*8)] = pa[p];
        }
        #pragma unroll
        for (int p = 0; p < 2; ++p) {
            int r = sr + p*32;
            *(bf8_t*)&Bs[r*64 + ((sc_ ^ (r&7))*8)] = pb[p];
        }
        __syncthreads();
        // prefetch next k-tile (overlaps with compute below)
        if (k0 + 64 < K) {
            #pragma unroll
            for (int p = 0; p < 4; ++p) {
                int r = sr + p*32;
                int gr = m0 + r;
                if (GUARD) gr = (gr < M) ? gr : (M-1);
                pa[p] = *(const bf8_t*)(A + (size_t)gr*K + k0 + 64 + sc_*8);
            }
            #pragma unroll
            for (int p = 0; p < 2; ++p)
                pb[p] = *(const bf8_t*)(Wt + (size_t)(n0 + sr + p*32)*K + k0 + 64 + sc_*8);
        }
        #pragma unroll
        for (int kc = 0; kc < 2; ++kc) {
            const int cg = kc*4 + quad;
            bf8_t af[4], bfr[2];
            #pragma unroll
            for (int mt = 0; mt < 4; ++mt) {
                int r = wm + mt*16 + l16;
                af[mt] = *(const bf8_t*)&As[r*64 + ((cg ^ (r&7))*8)];
            }
            #pragma unroll
            for (int nt = 0; nt < 2; ++nt) {
                int r = wn + nt*16 + l16;
                bfr[nt] = *(const bf8_t*)&Bs[r*64 + ((cg ^ (r&7))*8)];
            }
            #pragma unroll
            for (int mt = 0; mt < 4; ++mt)
                #pragma unroll
                for (int nt = 0; nt < 2; ++nt)
                    acc[mt][nt] = __builtin_amdgcn_mfma_f32_16x16x32_bf16(af[mt], bfr[nt], acc[mt][nt], 0, 0, 0);
        }
        __syncthreads();
    }

    if (VT == 1 && (n0 >> 9) == 2) {
        // self V: VtG[((b*8+h)*64 + d)*SEQ + tok], 4 tokens per 8B store
        bf16* vt = (bf16*)outs.p[2];
        #pragma unroll
        for (int mt = 0; mt < 4; ++mt) {
            int row = m0 + wm + mt*16 + quad*4;
            int bb = row >> 12, tok = row & 4095;
            #pragma unroll
            for (int nt = 0; nt < 2; ++nt) {
                int c = lc0 + wn + nt*16 + l16;
                int h = c >> 6, d = c & 63;
                uint2 w;
                w.x = packbf2(acc[mt][nt][0], acc[mt][nt][1]);
                w.y = packbf2(acc[mt][nt][2], acc[mt][nt][3]);
                *(uint2*)(vt + ((size_t)((bb*8 + h)*64 + d))*SEQ + tok) = w;
            }
        }
        return;
    }
    if (VT == 2 && (n0 >> 9) == 1) {
        // cross V: VtG2[((b*8+h)*64 + d)*128 + t], scalar (batch boundary at 77)
        bf16* vt = (bf16*)outs.p[1];
        #pragma unroll
        for (int mt = 0; mt < 4; ++mt) {
            #pragma unroll
            for (int r_ = 0; r_ < 4; ++r_) {
                int row = m0 + wm + mt*16 + quad*4 + r_;
                if (row >= NCTX) continue;
                int bb = (row >= CTXLEN) ? 1 : 0;
                int t  = row - bb*CTXLEN;
                #pragma unroll
                for (int nt = 0; nt < 2; ++nt) {
                    int c = lc0 + wn + nt*16 + l16;
                    int h = c >> 6, d = c & 63;
                    vt[((size_t)((bb*8 + h)*64 + d))*128 + t] = f2b(acc[mt][nt][r_]);
                }
            }
        }
        return;
    }

    #pragma unroll
    for (int mt = 0; mt < 4; ++mt) {
        #pragma unroll
        for (int r_ = 0; r_ < 4; ++r_) {
            int row = m0 + wm + mt*16 + quad*4 + r_;
            if (GUARD && row >= M) continue;
            size_t rb = (size_t)row * 512;
            #pragma unroll
            for (int nt = 0; nt < 2; ++nt) {
                int col = lc0 + wn + nt*16 + l16;
                float v = acc[mt][nt][r_];
                if (bias) v += bias[col];
                if (RESID) v += resid[rb + col];
                stf(&outp[rb + col], v);
            }
        }
    }
}

// ---------------- MFMA GEGLU with register-prefetch double-buffer (R10 form) ----------------
__global__ __launch_bounds__(256)
void geglu_mfma_kernel(const bf16* __restrict__ A, const bf16* __restrict__ WtG,
                       const float* __restrict__ bias, bf16* __restrict__ outp)
{
    __shared__ __align__(16) unsigned short As[128*64];
    __shared__ __align__(16) unsigned short Bys[64*64];
    __shared__ __align__(16) unsigned short Bgs[64*64];
    const int tid  = threadIdx.x;
    const int wave = tid >> 6, lane = tid & 63;
    const int l16  = lane & 15, quad = lane >> 4;
    const int m0 = blockIdx.y * 128, n0 = blockIdx.x * 64;
    const int sr = tid >> 3, sc_ = tid & 7;

    f4_t accy[2][4], accg[2][4];
    #pragma unroll
    for (int i = 0; i < 2; ++i)
        #pragma unroll
        for (int j = 0; j < 4; ++j) { accy[i][j] = f4_t{0,0,0,0}; accg[i][j] = f4_t{0,0,0,0}; }

    bf8_t pa[4], py[2], pg[2];
    #pragma unroll
    for (int p = 0; p < 4; ++p)
        pa[p] = *(const bf8_t*)(A + (size_t)(m0 + sr + p*32)*DIM + sc_*8);
    #pragma unroll
    for (int p = 0; p < 2; ++p) {
        py[p] = *(const bf8_t*)(WtG + (size_t)(n0 + sr + p*32)*DIM + sc_*8);
        pg[p] = *(const bf8_t*)(WtG + (size_t)(2048 + n0 + sr + p*32)*DIM + sc_*8);
    }

    for (int k0 = 0; k0 < DIM; k0 += 64) {
        #pragma unroll
        for (int p = 0; p < 4; ++p) {
            int r = sr + p*32;
            *(bf8_t*)&As[r*64 + ((sc_ ^ (r&7))*8)] = pa[p];
        }
        #pragma unroll
        for (int p = 0; p < 2; ++p) {
            int r = sr + p*32;
            *(bf8_t*)&Bys[r*64 + ((sc_ ^ (r&7))*8)] = py[p];
            *(bf8_t*)&Bgs[r*64 + ((sc_ ^ (r&7))*8)] = pg[p];
        }
        __syncthreads();
        if (k0 + 64 < DIM) {
            #pragma unroll
            for (int p = 0; p < 4; ++p)
                pa[p] = *(const bf8_t*)(A + (size_t)(m0 + sr + p*32)*DIM + k0 + 64 + sc_*8);
            #pragma unroll
            for (int p = 0; p < 2; ++p) {
                py[p] = *(const bf8_t*)(WtG + (size_t)(n0 + sr + p*32)*DIM + k0 + 64 + sc_*8);
                pg[p] = *(const bf8_t*)(WtG + (size_t)(2048 + n0 + sr + p*32)*DIM + k0 + 64 + sc_*8);
            }
        }
        #pragma unroll
        for (int kc = 0; kc < 2; ++kc) {
            const int cg = kc*4 + quad;
            bf8_t af[2];
            #pragma unroll
            for (int mt = 0; mt < 2; ++mt) {
                int r = wave*32 + mt*16 + l16;
                af[mt] = *(const bf8_t*)&As[r*64 + ((cg ^ (r&7))*8)];
            }
            #pragma unroll
            for (int nt = 0; nt < 4; ++nt) {
                int r = nt*16 + l16;
                bf8_t by = *(const bf8_t*)&Bys[r*64 + ((cg ^ (r&7))*8)];
                bf8_t bg = *(const bf8_t*)&Bgs[r*64 + ((cg ^ (r&7))*8)];
                #pragma unroll
                for (int mt = 0; mt < 2; ++mt) {
                    accy[mt][nt] = __builtin_amdgcn_mfma_f32_16x16x32_bf16(af[mt], by, accy[mt][nt], 0, 0, 0);
                    accg[mt][nt] = __builtin_amdgcn_mfma_f32_16x16x32_bf16(af[mt], bg, accg[mt][nt], 0, 0, 0);
                }
            }
        }
        __syncthreads();
    }

    #pragma unroll
    for (int mt = 0; mt < 2; ++mt) {
        #pragma unroll
        for (int r_ = 0; r_ < 4; ++r_) {
            int row = m0 + wave*32 + mt*16 + quad*4 + r_;
            size_t rb = (size_t)row * 2048;
            #pragma unroll
            for (int nt = 0; nt < 4; ++nt) {
                int col = n0 + nt*16 + l16;
                float y = accy[mt][nt][r_] + bias[col];
                float g = accg[mt][nt][r_] + bias[2048 + col];
                float t = tanhf(0.7978845608f*g*(1.f + 0.044715f*g*g));
                outp[rb + col] = f2b(y * 0.5f * g * (1.f + t));
            }
        }
    }
}

// ---------------- MFMA flash attention (R10 structure, measured-best core) ----------------
// KVBLK=64, Ks/Vts[64*64], Ps[8][16*64], 2 barriers/tile. R17's KVBLK=128
// tripled LDS bank conflicts (4.2M -> 14.7M) and cost 8.5us -- reverted.
__global__ __launch_bounds__(512)
void attn_mfma_kernel(const bf16* __restrict__ Qm, const bf16* __restrict__ Km,
                      const bf16* __restrict__ VtG, bf16* __restrict__ Om,
                      int T, int vpitch)
{
    __shared__ __align__(16) unsigned short Ks[64*64];
    __shared__ __align__(16) unsigned short Vts[64*64];
    __shared__ __align__(16) unsigned short Ps[8][16*64];

    const int tid  = threadIdx.x;
    const int wave = tid >> 6, lane = tid & 63;
    const int l16  = lane & 15, quad = lane >> 4;
    const int b = blockIdx.z, h = blockIdx.y;
    const int qblk = blockIdx.x * 128;
    const int sr = tid >> 3, sc_ = tid & 7;   // staging: row 0..63, chunk 0..7

    bf8_t ones;
    #pragma unroll
    for (int j = 0; j < 8; ++j) ((unsigned short*)&ones)[j] = 0x3F80;

    // Q fragments (B-operand layout), pre-scaled by D^-0.5 * log2(e)
    bf8_t qf[2];
    {
        const bf16* qp = Qm + ((size_t)(b*SEQ + qblk + wave*16 + l16))*DIM + h*HD + quad*8;
        #pragma unroll
        for (int kc = 0; kc < 2; ++kc) {
            bf8_t v = *(const bf8_t*)(qp + kc*32);
            unsigned short* u = (unsigned short*)&v;
            unsigned int* w = (unsigned int*)&v;
            #pragma unroll
            for (int j = 0; j < 4; ++j) {
                float f0 = b2f(*(bf16*)&u[2*j])   * 0.1803368801f;
                float f1 = b2f(*(bf16*)&u[2*j+1]) * 0.1803368801f;
                w[j] = packbf2(f0, f1);
            }
            qf[kc] = v;
        }
    }

    f4_t o[4];
    #pragma unroll
    for (int dt = 0; dt < 4; ++dt) o[dt] = f4_t{0,0,0,0};
    f4_t lacc = {0,0,0,0};

    const bf16* Kbase = Km + (size_t)b*T*DIM + h*HD;
    const bf16* Vbase = VtG + ((size_t)((b*8 + h)*64 + sr))*vpitch;

    // prologue: load tile 0 into registers
    bf8_t kq, vq;
    kq = bf8_t{0,0,0,0,0,0,0,0};
    if (sr < T) kq = *(const bf8_t*)(Kbase + (size_t)sr*DIM + sc_*8);
    vq = *(const bf8_t*)(Vbase + sc_*8);

    const int ntiles = (T + 63) >> 6;
    for (int t0 = 0; t0 < ntiles; ++t0) {
        const int kb = t0 << 6;
        // ---- regs -> LDS (swizzled b128) ----
        *(bf8_t*)&Ks[sr*64 + ((sc_ ^ (sr&7))*8)]  = kq;
        *(bf8_t*)&Vts[sr*64 + ((sc_ ^ (sr&7))*8)] = vq;
        __syncthreads();
        // ---- prefetch next tile (overlaps compute) ----
        if (t0 + 1 < ntiles) {
            int gk = kb + 64 + sr;
            kq = bf8_t{0,0,0,0,0,0,0,0};
            if (gk < T) kq = *(const bf8_t*)(Kbase + (size_t)gk*DIM + sc_*8);
            vq = *(const bf8_t*)(Vbase + kb + 64 + sc_*8);
        }

        bf8_t kf[4][2], vf[4][2];
        #pragma unroll
        for (int t = 0; t < 4; ++t) {
            int r = t*16 + l16;
            #pragma unroll
            for (int kc = 0; kc < 2; ++kc) {
                int cg = kc*4 + quad;
                kf[t][kc] = *(const bf8_t*)&Ks[r*64 + ((cg ^ (r&7))*8)];
                vf[t][kc] = *(const bf8_t*)&Vts[r*64 + ((cg ^ (r&7))*8)];
            }
        }
        const bool tail = (kb + 64 > T);

        f4_t sc4[4];
        #pragma unroll
        for (int km = 0; km < 4; ++km) {
            f4_t c = {0,0,0,0};
            c = __builtin_amdgcn_mfma_f32_16x16x32_bf16(kf[km][0], qf[0], c, 0, 0, 0);
            c = __builtin_amdgcn_mfma_f32_16x16x32_bf16(kf[km][1], qf[1], c, 0, 0, 0);
            sc4[km] = c;
        }
        if (tail) {
            #pragma unroll
            for (int km = 0; km < 4; ++km)
                #pragma unroll
                for (int r = 0; r < 4; ++r)
                    if (kb + km*16 + quad*4 + r >= T) sc4[km][r] = -1e30f;
        }
        #pragma unroll
        for (int km = 0; km < 4; ++km) {
            uint2 w;
            w.x = packbf2(exp2f(sc4[km][0]), exp2f(sc4[km][1]));
            w.y = packbf2(exp2f(sc4[km][2]), exp2f(sc4[km][3]));
            int chunk = 2*km + (quad >> 1);
            int a = l16*64 + ((chunk ^ (l16 & 7))*8) + (quad & 1)*4;
            *(uint2*)&Ps[wave][a] = w;
        }
        #pragma unroll
        for (int kc = 0; kc < 2; ++kc) {
            int cg = kc*4 + quad;
            bf8_t pf = *(const bf8_t*)&Ps[wave][l16*64 + ((cg ^ (l16 & 7))*8)];
            lacc = __builtin_amdgcn_mfma_f32_16x16x32_bf16(ones, pf, lacc, 0, 0, 0);
            #pragma unroll
            for (int dt = 0; dt < 4; ++dt)
                o[dt] = __builtin_amdgcn_mfma_f32_16x16x32_bf16(vf[dt][kc], pf, o[dt], 0, 0, 0);
        }
        __syncthreads();
    }

    {
        float inv = 1.f / lacc[0];
        int tok = qblk + wave*16 + l16;
        size_t base = ((size_t)(b*SEQ + tok))*DIM + h*HD;
        #pragma unroll
        for (int dt = 0; dt < 4; ++dt) {
            uint2 w;
            w.x = packbf2(o[dt][0]*inv, o[dt][1]*inv);
            w.y = packbf2(o[dt][2]*inv, o[dt][3]*inv);
            *(uint2*)(Om + base + dt*16 + quad*4) = w;
        }
    }
}

extern "C" void kernel_launch(void* const* d_in, const int* in_sizes, int n_in,
                              void* d_out, int out_size, void* d_ws, size_t ws_size,
                              hipStream_t stream)
{
    (void)in_sizes; (void)n_in; (void)out_size; (void)ws_size;
    const float* x    = (const float*)d_in[0];
    const float* ctx  = (const float*)d_in[1];
    const float* ln1g = (const float*)d_in[2];
    const float* ln1b = (const float*)d_in[3];
    const float* wq1  = (const float*)d_in[4];
    const float* wk1  = (const float*)d_in[5];
    const float* wv1  = (const float*)d_in[6];
    const float* wo1  = (const float*)d_in[7];
    const float* bo1  = (const float*)d_in[8];
    const float* ln2g = (const float*)d_in[9];
    const float* ln2b = (const float*)d_in[10];
    const float* wq2  = (const float*)d_in[11];
    const float* wk2  = (const float*)d_in[12];
    const float* wv2  = (const float*)d_in[13];
    const float* wo2  = (const float*)d_in[14];
    const float* bo2  = (const float*)d_in[15];
    const float* ln3g = (const float*)d_in[16];
    const float* ln3b = (const float*)d_in[17];
    const float* gw   = (const float*)d_in[18];
    const float* gb   = (const float*)d_in[19];
    const float* ow   = (const float*)d_in[20];
    const float* ob   = (const float*)d_in[21];
    float* out = (float*)d_out;

    char* ws = (char*)d_ws;
    bf16* An  = (bf16*)(ws);
    bf16* Qb  = (bf16*)(ws + ((size_t)8<<20));
    bf16* Kb  = (bf16*)(ws + ((size_t)16<<20));
    bf16* Ob  = (bf16*)(ws + ((size_t)32<<20));
    bf16* FF  = Qb;
    float* Hf = out;
    bf16* WT  = (bf16*)(ws + ((size_t)40<<20));
    bf16* wq1T = WT + 0*262144, *wk1T = WT + 1*262144, *wv1T = WT + 2*262144, *wo1T = WT + 3*262144;
    bf16* wq2T = WT + 4*262144, *wk2T = WT + 5*262144, *wv2T = WT + 6*262144, *wo2T = WT + 7*262144;
    bf16* gwT  = (bf16*)(ws + ((size_t)44<<20));
    bf16* owT  = (bf16*)(ws + ((size_t)48<<20));
    bf16* ctxb = (bf16*)(ws + ((size_t)50<<20));
    bf16* VtG2 = (bf16*)(ws + ((size_t)50<<20) + ((size_t)512<<10));
    bf16* VtG  = (bf16*)(ws + ((size_t)52<<20));   // written by QKV epilogue

    dim3 blk(256);
    dim3 blkA(512);

    // ---- fused prep: weights + ctx cast + LN1 (1 launch) ----
    PrepArgs pa;
    pa.src8[0]=wq1; pa.src8[1]=wk1; pa.src8[2]=wv1; pa.src8[3]=wo1;
    pa.src8[4]=wq2; pa.src8[5]=wk2; pa.src8[6]=wv2; pa.src8[7]=wo2;
    pa.dst8[0]=wq1T; pa.dst8[1]=wk1T; pa.dst8[2]=wv1T; pa.dst8[3]=wo1T;
    pa.dst8[4]=wq2T; pa.dst8[5]=wk2T; pa.dst8[6]=wv2T; pa.dst8[7]=wo2T;
    pa.gw=gw; pa.gwT=gwT; pa.ow=ow; pa.owT=owT; pa.ctx=ctx; pa.ctxb=ctxb;
    pa.x=x; pa.lng=ln1g; pa.lnb=ln1b; pa.An=An;
    prep_kernel<<<dim3(7476), blk, 0, stream>>>(pa);

    dim3 gLN(NTOK/4);
    dim3 gQKV(24, 64);        // N=1536 -> Qb, Kb, VtG (V written transposed)
    dim3 gG(8, 64);           // N=512
    dim3 gKVx(16, 2);         // N=1024, M=154 (guarded) -> Kb, VtG2 (V transposed)
    dim3 gGEGLU(32, 64);
    dim3 gATT(SEQ/128, NHEAD, BATCH);
    OutPtrs oQKV{{Qb, Kb, VtG}};
    OutPtrs oKVx{{Kb, VtG2, nullptr}};
    OutPtrs oQ{{Qb, nullptr, nullptr}};
    OutPtrs oH{{Hf, nullptr, nullptr}};
    OutPtrs oOut{{out, nullptr, nullptr}};

    // ---- self-attention ----
    gemm_mfma_kernel<0,bf16,false,1><<<gQKV, blk, 0, stream>>>(An, wq1T, nullptr, nullptr, oQKV, NTOK, DIM);
    attn_mfma_kernel<<<gATT, blkA, 0, stream>>>(Qb, Kb, VtG, Ob, SEQ, SEQ);
    gemm_mfma_kernel<1,float,false,0><<<gG, blk, 0, stream>>>(Ob, wo1T, bo1, x, oH, NTOK, DIM);

    // ---- cross-attention ----
    ln_kernel<<<gLN, blk, 0, stream>>>(Hf, ln2g, ln2b, An, NTOK);
    gemm_mfma_kernel<0,bf16,false,0><<<gG, blk, 0, stream>>>(An, wq2T, nullptr, nullptr, oQ, NTOK, DIM);
    gemm_mfma_kernel<0,bf16,true,2><<<gKVx, blk, 0, stream>>>(ctxb, wk2T, nullptr, nullptr, oKVx, NCTX, DIM);
    attn_mfma_kernel<<<gATT, blkA, 0, stream>>>(Qb, Kb, VtG2, Ob, CTXLEN, 128);
    gemm_mfma_kernel<1,float,false,0><<<gG, blk, 0, stream>>>(Ob, wo2T, bo2, Hf, oH, NTOK, DIM);

    // ---- GEGLU FFN + output projection ----
    ln_kernel<<<gLN, blk, 0, stream>>>(Hf, ln3g, ln3b, An, NTOK);
    geglu_mfma_kernel<<<gGEGLU, blk, 0, stream>>>(An, gwT, gb, FF);
    gemm_mfma_kernel<1,float,false,0><<<gG, blk, 0, stream>>>(FF, owT, ob, Hf, oOut, NTOK, 2048);
}

// Round 10
// 451.582 us; speedup vs baseline: 1.0444x; 1.0444x over previous
//
#include <hip/hip_runtime.h>
#include <hip/hip_bf16.h>
#include <math.h>

#define DIM 512
#define NHEAD 8
#define HD 64
#define BATCH 2
#define SEQ 4096
#define CTXLEN 77
#define NTOK (BATCH*SEQ)     // 8192
#define NCTX (BATCH*CTXLEN)  // 154

typedef __hip_bfloat16 bf16;
typedef __attribute__((ext_vector_type(8))) short bf8_t;   // 8 bf16 (4 VGPRs)
typedef __attribute__((ext_vector_type(4))) float f4_t;    // 4 fp32 acc

__device__ __forceinline__ float b2f(bf16 v){ return __bfloat162float(v); }
__device__ __forceinline__ bf16  f2b(float v){ return __float2bfloat16(v); }
// fast bf16 pair pack: round-half-up + one v_perm_b32; low element = a, high = b
__device__ __forceinline__ unsigned int packbf2(float a, float b){
    unsigned int au = __float_as_uint(a) + 0x8000u;
    unsigned int bu = __float_as_uint(b) + 0x8000u;
    return __builtin_amdgcn_perm(bu, au, 0x07060302u);
}
__device__ __forceinline__ void  stf(float* p, float v){ *p = v; }
__device__ __forceinline__ void  stf(bf16* p, float v){ *p = f2b(v); }

// ---------------- LayerNorm ----------------
__global__ __launch_bounds__(256)
void ln_kernel(const float* __restrict__ x, const float* __restrict__ g,
               const float* __restrict__ b, bf16* __restrict__ out, int nrows)
{
    int row  = blockIdx.x * 4 + (threadIdx.x >> 6);
    int lane = threadIdx.x & 63;
    if (row >= nrows) return;
    const float* xr = x + (size_t)row * DIM;
    float v[8];
    float s = 0.f, sq = 0.f;
    #pragma unroll
    for (int j = 0; j < 8; ++j) {
        float f = xr[lane + 64*j];
        v[j] = f; s += f; sq += f*f;
    }
    #pragma unroll
    for (int off = 32; off; off >>= 1) {
        s  += __shfl_xor(s,  off);
        sq += __shfl_xor(sq, off);
    }
    float mean = s * (1.f/DIM);
    float var  = sq * (1.f/DIM) - mean*mean;
    float rstd = rsqrtf(var + 1e-5f);
    bf16* orow = out + (size_t)row * DIM;
    #pragma unroll
    for (int j = 0; j < 8; ++j) {
        int c = lane + 64*j;
        orow[c] = f2b((v[j]-mean)*rstd*g[c] + b[c]);
    }
}

// ---------------- fused weight prep: 8x 512x512 transposes + gw + ow + ctx cast ----------------
// One launch replaces 4. Flat block ranges:
//   [0,2048)    : 8 attention weight transposes (512x512, 16x16 tiles each)
//   [2048,4096) : gw transpose  (K=512 -> N=4096, 128x16 tiles)
//   [4096,5120) : ow transpose  (K=2048 -> N=512, 16x64 tiles)
//   [5120,5428) : ctx f32->bf16 cast (308*256 == 78848 == NCTX*DIM exactly)
struct PrepArgs {
    const float* src8[8]; bf16* dst8[8];
    const float* gw; bf16* gwT;
    const float* ow; bf16* owT;
    const float* ctx; bf16* ctxb;
};
__global__ __launch_bounds__(256)
void prep_kernel(PrepArgs a)
{
    __shared__ float tile[32][33];
    const int bid = blockIdx.x;
    const int tx = threadIdx.x & 31, ty = threadIdx.x >> 5;
    const float* W; bf16* Wt; int K, N, n0, k0;
    if (bid < 2048) {
        int z = bid >> 8, t = bid & 255;
        W = a.src8[z]; Wt = a.dst8[z]; K = 512; N = 512;
        n0 = (t & 15)*32; k0 = (t >> 4)*32;
    } else if (bid < 4096) {
        int t = bid - 2048;
        W = a.gw; Wt = a.gwT; K = 512; N = 4096;
        n0 = (t & 127)*32; k0 = (t >> 7)*32;
    } else if (bid < 5120) {
        int t = bid - 4096;
        W = a.ow; Wt = a.owT; K = 2048; N = 512;
        n0 = (t & 15)*32; k0 = (t >> 4)*32;
    } else {
        int i = (bid - 5120)*256 + threadIdx.x;
        a.ctxb[i] = f2b(a.ctx[i]);
        return;
    }
    #pragma unroll
    for (int p = 0; p < 4; ++p)
        tile[ty + p*8][tx] = W[(size_t)(k0 + ty + p*8)*N + n0 + tx];
    __syncthreads();
    #pragma unroll
    for (int p = 0; p < 4; ++p)
        Wt[(size_t)(n0 + ty + p*8)*K + k0 + tx] = f2b(tile[tx][ty + p*8]);
}

// ---------------- V transpose (cross-attn only; tiny) ----------------
__global__ __launch_bounds__(256)
void v_transpose_kernel(const bf16* __restrict__ V, bf16* __restrict__ Vt, int T, int pitch)
{
    __shared__ __align__(16) unsigned short tile[64*64];
    const int tid = threadIdx.x;
    const int b = blockIdx.z, h = blockIdx.y;
    const int t0 = blockIdx.x * 64;
    #pragma unroll
    for (int it = 0; it < 2; ++it) {
        int e = tid + it*256;
        int t = e >> 3, c = e & 7;
        int gk = t0 + t;
        bf8_t v = {0,0,0,0,0,0,0,0};
        if (gk < T) v = *(const bf8_t*)(V + ((size_t)(b*T + gk))*DIM + h*HD + c*8);
        *(bf8_t*)&tile[t*64 + c*8] = v;
    }
    __syncthreads();
    #pragma unroll
    for (int it = 0; it < 2; ++it) {
        int e = tid + it*256;
        int d = e & 63, oc = e >> 6;
        unsigned short tmp[8];
        #pragma unroll
        for (int j = 0; j < 8; ++j) tmp[j] = tile[(oc*8 + j)*64 + d];
        *(bf8_t*)(Vt + ((size_t)((b*8 + h)*64 + d))*pitch + t0 + oc*8) = *(bf8_t*)tmp;
    }
}

// ---------------- MFMA GEMM with register-prefetch double-buffer (R10 form) ----------------
// VT: blocks whose output lands in p[2] (V of QKV) write the accumulator
// directly in the attention's transposed V layout [ (b*8+h)*64+d ][ tok ]
// (lane holds 4 consecutive tokens for fixed d -> packed 8B stores), which
// deletes the separate v_transpose kernel and the Vb roundtrip.
struct OutPtrs { void* p[3]; };
template<int RESID, typename OUTT, bool GUARD, bool VT>
__global__ __launch_bounds__(256)
void gemm_mfma_kernel(const bf16* __restrict__ A, const bf16* __restrict__ Wt,
                      const float* __restrict__ bias, const float* __restrict__ resid,
                      OutPtrs outs, int M, int K)
{
    __shared__ __align__(16) unsigned short As[128*64];
    __shared__ __align__(16) unsigned short Bs[64*64];
    const int tid  = threadIdx.x;
    const int wave = tid >> 6, lane = tid & 63;
    const int l16  = lane & 15, quad = lane >> 4;
    const int wm = (wave >> 1) * 64, wn = (wave & 1) * 32;
    const int m0 = blockIdx.y * 128, n0 = blockIdx.x * 64;
    OUTT* outp = (OUTT*)outs.p[n0 >> 9];
    const int lc0 = n0 & 511;
    const int sr = tid >> 3, sc_ = tid & 7;   // staging row/chunk

    f4_t acc[4][2];
    #pragma unroll
    for (int i = 0; i < 4; ++i) { acc[i][0] = f4_t{0,0,0,0}; acc[i][1] = f4_t{0,0,0,0}; }

    // prologue: prefetch k0=0 tiles into registers
    bf8_t pa[4], pb[2];
    #pragma unroll
    for (int p = 0; p < 4; ++p) {
        int r = sr + p*32;
        int gr = m0 + r;
        if (GUARD) gr = (gr < M) ? gr : (M-1);
        pa[p] = *(const bf8_t*)(A + (size_t)gr*K + sc_*8);
    }
    #pragma unroll
    for (int p = 0; p < 2; ++p)
        pb[p] = *(const bf8_t*)(Wt + (size_t)(n0 + sr + p*32)*K + sc_*8);

    for (int k0 = 0; k0 < K; k0 += 64) {
        // regs -> LDS
        #pragma unroll
        for (int p = 0; p < 4; ++p) {
            int r = sr + p*32;
            *(bf8_t*)&As[r*64 + ((sc_ ^ (r&7))*8)] = pa[p];
        }
        #pragma unroll
        for (int p = 0; p < 2; ++p) {
            int r = sr + p*32;
            *(bf8_t*)&Bs[r*64 + ((sc_ ^ (r&7))*8)] = pb[p];
        }
        __syncthreads();
        // prefetch next k-tile (overlaps with compute below)
        if (k0 + 64 < K) {
            #pragma unroll
            for (int p = 0; p < 4; ++p) {
                int r = sr + p*32;
                int gr = m0 + r;
                if (GUARD) gr = (gr < M) ? gr : (M-1);
                pa[p] = *(const bf8_t*)(A + (size_t)gr*K + k0 + 64 + sc_*8);
            }
            #pragma unroll
            for (int p = 0; p < 2; ++p)
                pb[p] = *(const bf8_t*)(Wt + (size_t)(n0 + sr + p*32)*K + k0 + 64 + sc_*8);
        }
        #pragma unroll
        for (int kc = 0; kc < 2; ++kc) {
            const int cg = kc*4 + quad;
            bf8_t af[4], bfr[2];
            #pragma unroll
            for (int mt = 0; mt < 4; ++mt) {
                int r = wm + mt*16 + l16;
                af[mt] = *(const bf8_t*)&As[r*64 + ((cg ^ (r&7))*8)];
            }
            #pragma unroll
            for (int nt = 0; nt < 2; ++nt) {
                int r = wn + nt*16 + l16;
                bfr[nt] = *(const bf8_t*)&Bs[r*64 + ((cg ^ (r&7))*8)];
            }
            #pragma unroll
            for (int mt = 0; mt < 4; ++mt)
                #pragma unroll
                for (int nt = 0; nt < 2; ++nt)
                    acc[mt][nt] = __builtin_amdgcn_mfma_f32_16x16x32_bf16(af[mt], bfr[nt], acc[mt][nt], 0, 0, 0);
        }
        __syncthreads();
    }

    if (VT && (n0 >> 9) == 2) {
        // transposed V write: VtG[((b*8+h)*64 + d)*SEQ + tok], 4 tokens per store
        bf16* vt = (bf16*)outs.p[2];
        #pragma unroll
        for (int mt = 0; mt < 4; ++mt) {
            int row = m0 + wm + mt*16 + quad*4;
            int bb = row >> 12, tok = row & 4095;
            #pragma unroll
            for (int nt = 0; nt < 2; ++nt) {
                int c = lc0 + wn + nt*16 + l16;
                int h = c >> 6, d = c & 63;
                uint2 w;
                w.x = packbf2(acc[mt][nt][0], acc[mt][nt][1]);
                w.y = packbf2(acc[mt][nt][2], acc[mt][nt][3]);
                *(uint2*)(vt + ((size_t)((bb*8 + h)*64 + d))*SEQ + tok) = w;
            }
        }
        return;
    }

    #pragma unroll
    for (int mt = 0; mt < 4; ++mt) {
        #pragma unroll
        for (int r_ = 0; r_ < 4; ++r_) {
            int row = m0 + wm + mt*16 + quad*4 + r_;
            if (GUARD && row >= M) continue;
            size_t rb = (size_t)row * 512;
            #pragma unroll
            for (int nt = 0; nt < 2; ++nt) {
                int col = lc0 + wn + nt*16 + l16;
                float v = acc[mt][nt][r_];
                if (bias) v += bias[col];
                if (RESID) v += resid[rb + col];
                stf(&outp[rb + col], v);
            }
        }
    }
}

// ---------------- MFMA GEGLU with register-prefetch double-buffer (R10 form) ----------------
__global__ __launch_bounds__(256)
void geglu_mfma_kernel(const bf16* __restrict__ A, const bf16* __restrict__ WtG,
                       const float* __restrict__ bias, bf16* __restrict__ outp)
{
    __shared__ __align__(16) unsigned short As[128*64];
    __shared__ __align__(16) unsigned short Bys[64*64];
    __shared__ __align__(16) unsigned short Bgs[64*64];
    const int tid  = threadIdx.x;
    const int wave = tid >> 6, lane = tid & 63;
    const int l16  = lane & 15, quad = lane >> 4;
    const int m0 = blockIdx.y * 128, n0 = blockIdx.x * 64;
    const int sr = tid >> 3, sc_ = tid & 7;

    f4_t accy[2][4], accg[2][4];
    #pragma unroll
    for (int i = 0; i < 2; ++i)
        #pragma unroll
        for (int j = 0; j < 4; ++j) { accy[i][j] = f4_t{0,0,0,0}; accg[i][j] = f4_t{0,0,0,0}; }

    bf8_t pa[4], py[2], pg[2];
    #pragma unroll
    for (int p = 0; p < 4; ++p)
        pa[p] = *(const bf8_t*)(A + (size_t)(m0 + sr + p*32)*DIM + sc_*8);
    #pragma unroll
    for (int p = 0; p < 2; ++p) {
        py[p] = *(const bf8_t*)(WtG + (size_t)(n0 + sr + p*32)*DIM + sc_*8);
        pg[p] = *(const bf8_t*)(WtG + (size_t)(2048 + n0 + sr + p*32)*DIM + sc_*8);
    }

    for (int k0 = 0; k0 < DIM; k0 += 64) {
        #pragma unroll
        for (int p = 0; p < 4; ++p) {
            int r = sr + p*32;
            *(bf8_t*)&As[r*64 + ((sc_ ^ (r&7))*8)] = pa[p];
        }
        #pragma unroll
        for (int p = 0; p < 2; ++p) {
            int r = sr + p*32;
            *(bf8_t*)&Bys[r*64 + ((sc_ ^ (r&7))*8)] = py[p];
            *(bf8_t*)&Bgs[r*64 + ((sc_ ^ (r&7))*8)] = pg[p];
        }
        __syncthreads();
        if (k0 + 64 < DIM) {
            #pragma unroll
            for (int p = 0; p < 4; ++p)
                pa[p] = *(const bf8_t*)(A + (size_t)(m0 + sr + p*32)*DIM + k0 + 64 + sc_*8);
            #pragma unroll
            for (int p = 0; p < 2; ++p) {
                py[p] = *(const bf8_t*)(WtG + (size_t)(n0 + sr + p*32)*DIM + k0 + 64 + sc_*8);
                pg[p] = *(const bf8_t*)(WtG + (size_t)(2048 + n0 + sr + p*32)*DIM + k0 + 64 + sc_*8);
            }
        }
        #pragma unroll
        for (int kc = 0; kc < 2; ++kc) {
            const int cg = kc*4 + quad;
            bf8_t af[2];
            #pragma unroll
            for (int mt = 0; mt < 2; ++mt) {
                int r = wave*32 + mt*16 + l16;
                af[mt] = *(const bf8_t*)&As[r*64 + ((cg ^ (r&7))*8)];
            }
            #pragma unroll
            for (int nt = 0; nt < 4; ++nt) {
                int r = nt*16 + l16;
                bf8_t by = *(const bf8_t*)&Bys[r*64 + ((cg ^ (r&7))*8)];
                bf8_t bg = *(const bf8_t*)&Bgs[r*64 + ((cg ^ (r&7))*8)];
                #pragma unroll
                for (int mt = 0; mt < 2; ++mt) {
                    accy[mt][nt] = __builtin_amdgcn_mfma_f32_16x16x32_bf16(af[mt], by, accy[mt][nt], 0, 0, 0);
                    accg[mt][nt] = __builtin_amdgcn_mfma_f32_16x16x32_bf16(af[mt], bg, accg[mt][nt], 0, 0, 0);
                }
            }
        }
        __syncthreads();
    }

    #pragma unroll
    for (int mt = 0; mt < 2; ++mt) {
        #pragma unroll
        for (int r_ = 0; r_ < 4; ++r_) {
            int row = m0 + wave*32 + mt*16 + quad*4 + r_;
            size_t rb = (size_t)row * 2048;
            #pragma unroll
            for (int nt = 0; nt < 4; ++nt) {
                int col = n0 + nt*16 + l16;
                float y = accy[mt][nt][r_] + bias[col];
                float g = accg[mt][nt][r_] + bias[2048 + col];
                float t = tanhf(0.7978845608f*g*(1.f + 0.044715f*g*g));
                outp[rb + col] = f2b(y * 0.5f * g * (1.f + t));
            }
        }
    }
}

// ---------------- MFMA flash attention (R10 structure) ----------------
__global__ __launch_bounds__(512)
void attn_mfma_kernel(const bf16* __restrict__ Qm, const bf16* __restrict__ Km,
                      const bf16* __restrict__ VtG, bf16* __restrict__ Om,
                      int T, int vpitch)
{
    __shared__ __align__(16) unsigned short Ks[64*64];
    __shared__ __align__(16) unsigned short Vts[64*64];
    __shared__ __align__(16) unsigned short Ps[8][16*64];

    const int tid  = threadIdx.x;
    const int wave = tid >> 6, lane = tid & 63;
    const int l16  = lane & 15, quad = lane >> 4;
    const int b = blockIdx.z, h = blockIdx.y;
    const int qblk = blockIdx.x * 128;
    const int sr = tid >> 3, sc_ = tid & 7;   // staging: row 0..63, chunk 0..7

    bf8_t ones;
    #pragma unroll
    for (int j = 0; j < 8; ++j) ((unsigned short*)&ones)[j] = 0x3F80;

    // Q fragments (B-operand layout), pre-scaled by D^-0.5 * log2(e)
    bf8_t qf[2];
    {
        const bf16* qp = Qm + ((size_t)(b*SEQ + qblk + wave*16 + l16))*DIM + h*HD + quad*8;
        #pragma unroll
        for (int kc = 0; kc < 2; ++kc) {
            bf8_t v = *(const bf8_t*)(qp + kc*32);
            unsigned short* u = (unsigned short*)&v;
            unsigned int* w = (unsigned int*)&v;
            #pragma unroll
            for (int j = 0; j < 4; ++j) {
                float f0 = b2f(*(bf16*)&u[2*j])   * 0.1803368801f;
                float f1 = b2f(*(bf16*)&u[2*j+1]) * 0.1803368801f;
                w[j] = packbf2(f0, f1);
            }
            qf[kc] = v;
        }
    }

    f4_t o[4];
    #pragma unroll
    for (int dt = 0; dt < 4; ++dt) o[dt] = f4_t{0,0,0,0};
    f4_t lacc = {0,0,0,0};

    const bf16* Kbase = Km + (size_t)b*T*DIM + h*HD;
    const bf16* Vbase = VtG + ((size_t)((b*8 + h)*64 + sr))*vpitch;

    // prologue: load tile 0 into registers
    bf8_t kq, vq;
    kq = bf8_t{0,0,0,0,0,0,0,0};
    if (sr < T) kq = *(const bf8_t*)(Kbase + (size_t)sr*DIM + sc_*8);
    vq = *(const bf8_t*)(Vbase + sc_*8);

    const int ntiles = (T + 63) >> 6;
    for (int t0 = 0; t0 < ntiles; ++t0) {
        const int kb = t0 << 6;
        // ---- regs -> LDS (swizzled b128) ----
        *(bf8_t*)&Ks[sr*64 + ((sc_ ^ (sr&7))*8)]  = kq;
        *(bf8_t*)&Vts[sr*64 + ((sc_ ^ (sr&7))*8)] = vq;
        __syncthreads();
        // ---- prefetch next tile (overlaps compute) ----
        if (t0 + 1 < ntiles) {
            int gk = kb + 64 + sr;
            kq = bf8_t{0,0,0,0,0,0,0,0};
            if (gk < T) kq = *(const bf8_t*)(Kbase + (size_t)gk*DIM + sc_*8);
            vq = *(const bf8_t*)(Vbase + kb + 64 + sc_*8);
        }

        bf8_t kf[4][2], vf[4][2];
        #pragma unroll
        for (int t = 0; t < 4; ++t) {
            int r = t*16 + l16;
            #pragma unroll
            for (int kc = 0; kc < 2; ++kc) {
                int cg = kc*4 + quad;
                kf[t][kc] = *(const bf8_t*)&Ks[r*64 + ((cg ^ (r&7))*8)];
                vf[t][kc] = *(const bf8_t*)&Vts[r*64 + ((cg ^ (r&7))*8)];
            }
        }
        const bool tail = (kb + 64 > T);

        f4_t sc4[4];
        #pragma unroll
        for (int km = 0; km < 4; ++km) {
            f4_t c = {0,0,0,0};
            c = __builtin_amdgcn_mfma_f32_16x16x32_bf16(kf[km][0], qf[0], c, 0, 0, 0);
            c = __builtin_amdgcn_mfma_f32_16x16x32_bf16(kf[km][1], qf[1], c, 0, 0, 0);
            sc4[km] = c;
        }
        if (tail) {
            #pragma unroll
            for (int km = 0; km < 4; ++km)
                #pragma unroll
                for (int r = 0; r < 4; ++r)
                    if (kb + km*16 + quad*4 + r >= T) sc4[km][r] = -1e30f;
        }
        #pragma unroll
        for (int km = 0; km < 4; ++km) {
            uint2 w;
            w.x = packbf2(exp2f(sc4[km][0]), exp2f(sc4[km][1]));
            w.y = packbf2(exp2f(sc4[km][2]), exp2f(sc4[km][3]));
            int chunk = 2*km + (quad >> 1);
            int a = l16*64 + ((chunk ^ (l16 & 7))*8) + (quad & 1)*4;
            *(uint2*)&Ps[wave][a] = w;
        }
        #pragma unroll
        for (int kc = 0; kc < 2; ++kc) {
            int cg = kc*4 + quad;
            bf8_t pf = *(const bf8_t*)&Ps[wave][l16*64 + ((cg ^ (l16 & 7))*8)];
            lacc = __builtin_amdgcn_mfma_f32_16x16x32_bf16(ones, pf, lacc, 0, 0, 0);
            #pragma unroll
            for (int dt = 0; dt < 4; ++dt)
                o[dt] = __builtin_amdgcn_mfma_f32_16x16x32_bf16(vf[dt][kc], pf, o[dt], 0, 0, 0);
        }
        __syncthreads();
    }

    {
        float inv = 1.f / lacc[0];
        int tok = qblk + wave*16 + l16;
        size_t base = ((size_t)(b*SEQ + tok))*DIM + h*HD;
        #pragma unroll
        for (int dt = 0; dt < 4; ++dt) {
            uint2 w;
            w.x = packbf2(o[dt][0]*inv, o[dt][1]*inv);
            w.y = packbf2(o[dt][2]*inv, o[dt][3]*inv);
            *(uint2*)(Om + base + dt*16 + quad*4) = w;
        }
    }
}

extern "C" void kernel_launch(void* const* d_in, const int* in_sizes, int n_in,
                              void* d_out, int out_size, void* d_ws, size_t ws_size,
                              hipStream_t stream)
{
    (void)in_sizes; (void)n_in; (void)out_size; (void)ws_size;
    const float* x    = (const float*)d_in[0];
    const float* ctx  = (const float*)d_in[1];
    const float* ln1g = (const float*)d_in[2];
    const float* ln1b = (const float*)d_in[3];
    const float* wq1  = (const float*)d_in[4];
    const float* wk1  = (const float*)d_in[5];
    const float* wv1  = (const float*)d_in[6];
    const float* wo1  = (const float*)d_in[7];
    const float* bo1  = (const float*)d_in[8];
    const float* ln2g = (const float*)d_in[9];
    const float* ln2b = (const float*)d_in[10];
    const float* wq2  = (const float*)d_in[11];
    const float* wk2  = (const float*)d_in[12];
    const float* wv2  = (const float*)d_in[13];
    const float* wo2  = (const float*)d_in[14];
    const float* bo2  = (const float*)d_in[15];
    const float* ln3g = (const float*)d_in[16];
    const float* ln3b = (const float*)d_in[17];
    const float* gw   = (const float*)d_in[18];
    const float* gb   = (const float*)d_in[19];
    const float* ow   = (const float*)d_in[20];
    const float* ob   = (const float*)d_in[21];
    float* out = (float*)d_out;

    char* ws = (char*)d_ws;
    bf16* An  = (bf16*)(ws);
    bf16* Qb  = (bf16*)(ws + ((size_t)8<<20));
    bf16* Kb  = (bf16*)(ws + ((size_t)16<<20));
    bf16* Vb  = (bf16*)(ws + ((size_t)24<<20));
    bf16* Ob  = (bf16*)(ws + ((size_t)32<<20));
    bf16* FF  = Qb;
    float* Hf = out;
    bf16* WT  = (bf16*)(ws + ((size_t)40<<20));
    bf16* wq1T = WT + 0*262144, *wk1T = WT + 1*262144, *wv1T = WT + 2*262144, *wo1T = WT + 3*262144;
    bf16* wq2T = WT + 4*262144, *wk2T = WT + 5*262144, *wv2T = WT + 6*262144, *wo2T = WT + 7*262144;
    bf16* gwT  = (bf16*)(ws + ((size_t)44<<20));
    bf16* owT  = (bf16*)(ws + ((size_t)48<<20));
    bf16* ctxb = (bf16*)(ws + ((size_t)50<<20));
    bf16* VtG2 = (bf16*)(ws + ((size_t)50<<20) + ((size_t)512<<10));
    bf16* VtG  = (bf16*)(ws + ((size_t)52<<20));   // own region: written by QKV epilogue

    dim3 blk(256);
    dim3 blkA(512);

    // ---- fused weight prep (1 launch instead of 4) ----
    PrepArgs pa;
    pa.src8[0]=wq1; pa.src8[1]=wk1; pa.src8[2]=wv1; pa.src8[3]=wo1;
    pa.src8[4]=wq2; pa.src8[5]=wk2; pa.src8[6]=wv2; pa.src8[7]=wo2;
    pa.dst8[0]=wq1T; pa.dst8[1]=wk1T; pa.dst8[2]=wv1T; pa.dst8[3]=wo1T;
    pa.dst8[4]=wq2T; pa.dst8[5]=wk2T; pa.dst8[6]=wv2T; pa.dst8[7]=wo2T;
    pa.gw=gw; pa.gwT=gwT; pa.ow=ow; pa.owT=owT; pa.ctx=ctx; pa.ctxb=ctxb;
    prep_kernel<<<dim3(5428), blk, 0, stream>>>(pa);

    dim3 gLN(NTOK/4);
    dim3 gQKV(24, 64);        // N=1536 -> Qb, Kb, VtG (V written transposed)
    dim3 gG(8, 64);           // N=512
    dim3 gKVx(16, 2);         // N=1024, M=154 (guarded) -> Kb,Vb
    dim3 gGEGLU(32, 64);
    dim3 gATT(SEQ/128, NHEAD, BATCH);
    OutPtrs oQKV{{Qb, Kb, VtG}};
    OutPtrs oKVx{{Kb, Vb, nullptr}};
    OutPtrs oQ{{Qb, nullptr, nullptr}};
    OutPtrs oH{{Hf, nullptr, nullptr}};
    OutPtrs oOut{{out, nullptr, nullptr}};

    // ---- self-attention ----
    ln_kernel<<<gLN, blk, 0, stream>>>(x, ln1g, ln1b, An, NTOK);
    gemm_mfma_kernel<0,bf16,false,true><<<gQKV, blk, 0, stream>>>(An, wq1T, nullptr, nullptr, oQKV, NTOK, DIM);
    attn_mfma_kernel<<<gATT, blkA, 0, stream>>>(Qb, Kb, VtG, Ob, SEQ, SEQ);
    gemm_mfma_kernel<1,float,false,false><<<gG, blk, 0, stream>>>(Ob, wo1T, bo1, x, oH, NTOK, DIM);

    // ---- cross-attention ----
    ln_kernel<<<gLN, blk, 0, stream>>>(Hf, ln2g, ln2b, An, NTOK);
    gemm_mfma_kernel<0,bf16,false,false><<<gG, blk, 0, stream>>>(An, wq2T, nullptr, nullptr, oQ, NTOK, DIM);
    gemm_mfma_kernel<0,bf16,true,false><<<gKVx, blk, 0, stream>>>(ctxb, wk2T, nullptr, nullptr, oKVx, NCTX, DIM);
    v_transpose_kernel<<<dim3(2, NHEAD, BATCH), blk, 0, stream>>>(Vb, VtG2, CTXLEN, 128);
    attn_mfma_kernel<<<gATT, blkA, 0, stream>>>(Qb, Kb, VtG2, Ob, CTXLEN, 128);
    gemm_mfma_kernel<1,float,false,false><<<gG, blk, 0, stream>>>(Ob, wo2T, bo2, Hf, oH, NTOK, DIM);

    // ---- GEGLU FFN + output projection ----
    ln_kernel<<<gLN, blk, 0, stream>>>(Hf, ln3g, ln3b, An, NTOK);
    geglu_mfma_kernel<<<gGEGLU, blk, 0, stream>>>(An, gwT, gb, FF);
    gemm_mfma_kernel<1,float,false,false><<<gG, blk, 0, stream>>>(FF, owT, ob, Hf, oOut, NTOK, 2048);
}